// Round 8
// baseline (82.700 us; speedup 1.0000x reference)
//
#include <hip/hip_runtime.h>
#include <hip/hip_bf16.h>

#define NNODE 100000
#define CIN   64
#define CHID  64
#define NREL  8
#define NGRP  6250     // NNODE / 16

typedef __attribute__((ext_vector_type(8))) short bf16x8;
typedef __attribute__((ext_vector_type(4))) float f32x4;
typedef unsigned long long u64;

__device__ __forceinline__ unsigned short f2bf(float f) {
    __hip_bfloat16 h = __float2bfloat16(f);
    return __builtin_bit_cast(unsigned short, h);
}
__device__ __forceinline__ float bf2f(unsigned short u) {
    unsigned int v = ((unsigned int)u) << 16;
    return __builtin_bit_cast(float, v);
}

// ---- fused prep: [0,6250) x->xb | [6250,6641) edge sort | [6641,6657) W pack ----
__global__ void k_prep(const float* __restrict__ x, const float* __restrict__ W,
                       const int* __restrict__ ptr, const int* __restrict__ idx,
                       const int* __restrict__ et,
                       unsigned short* __restrict__ xb, unsigned short* __restrict__ wf,
                       int* __restrict__ sidx, u64* __restrict__ typ4) {
    int b = blockIdx.x;
    if (b < 6250) {
        // x (f32) -> xb (bf16), 4 elems/thread
        int i = (b * 256 + threadIdx.x) * 4;
        float4 v = *reinterpret_cast<const float4*>(x + i);
        ushort4 o;
        o.x = f2bf(v.x); o.y = f2bf(v.y); o.z = f2bf(v.z); o.w = f2bf(v.w);
        *reinterpret_cast<ushort4*>(xb + i) = o;
    } else if (b < 6641) {
        // per-node counting sort of edges by type (deg==16 fast case)
        int node = (b - 6250) * 256 + threadIdx.x;
        if (node >= NNODE) return;
        int eb = ptr[node], en = ptr[node + 1];
        if (en - eb != 16) { typ4[node] = 0; return; }
        u64 cnt = 0;
#pragma unroll
        for (int ee = 0; ee < 16; ++ee)
            cnt += 1ull << (8 * et[eb + ee]);
        u64 pre = cnt * 0x0101010101010100ull;   // exclusive byte prefix sums
        u64 occ = 0, tp = 0;
#pragma unroll
        for (int ee = 0; ee < 16; ++ee) {
            int te = et[eb + ee];
            int sh = te * 8;
            int pos = (int)((pre >> sh) & 0xFF) + (int)((occ >> sh) & 0xFF);
            occ += 1ull << sh;
            sidx[eb + pos] = idx[eb + ee];
            tp |= (u64)te << (4 * pos);
        }
        typ4[node] = tp;
    } else {
        // W (f32 [8][64][64]) -> B-fragment bf16, flat k = r*64 + ki
        // tile = kt*4+nt; lane l: B[k = kt*32+(l>>4)*8+j][col = nt*16+(l&15)]
        int tid = (b - 6641) * 256 + threadIdx.x;
        if (tid >= 64 * 64) return;
        int tile = tid >> 6, lane = tid & 63;
        int kt = tile >> 2, nt = tile & 3;
        int kbase = kt * 32 + (lane >> 4) * 8;
        int col = nt * 16 + (lane & 15);
        unsigned short v[8];
#pragma unroll
        for (int j = 0; j < 8; ++j)
            v[j] = f2bf(W[(kbase + j) * 64 + col]);
        ushort4* dst = reinterpret_cast<ushort4*>(wf + (size_t)tid * 8);
        ushort4 lo, hi;
        lo.x = v[0]; lo.y = v[1]; lo.z = v[2]; lo.w = v[3];
        hi.x = v[4]; hi.y = v[5]; hi.z = v[6]; hi.w = v[7];
        dst[0] = lo; dst[1] = hi;
    }
}

// ---- main: block = 4 waves share one 16-node group; S[16][512] bf16 swizzled ----
// Fast path: sources read via SCALAR loads (wave-uniform sorted order) -> saddr-form
// gather loads (shared vaddr = lane*2, zero per-edge vector addressing); running-sum
// accumulate with wave-uniform run-boundary flushes to S[row][t*64+lane].
__launch_bounds__(256, 8)
__global__ void k_main(const unsigned short* __restrict__ xb,
                       const bf16x8* __restrict__ wf,
                       const int* __restrict__ ptr,
                       const int* __restrict__ sidx,
                       const u64* __restrict__ typ4,
                       const int* __restrict__ idx,
                       const int* __restrict__ et,
                       const int* __restrict__ hmap,
                       const float* __restrict__ hbuf,
                       float* __restrict__ out) {
    __shared__ __align__(16) unsigned short S[8192];   // 16 rows x 512 k, 16 KB

    int wave = __builtin_amdgcn_readfirstlane((int)(threadIdx.x >> 6));
    int lane = threadIdx.x & 63;
    int n0 = blockIdx.x * 16;
    int nbase = n0 + wave * 4;
    char* sb = reinterpret_cast<char*>(&S[0]);

    // zero S (types with no edges must read as 0)
    {
        f32x4 z = {0.f, 0.f, 0.f, 0.f};
        f32x4* sz = reinterpret_cast<f32x4*>(sb);
        sz[threadIdx.x]       = z;
        sz[threadIdx.x + 256] = z;
        sz[threadIdx.x + 512] = z;
        sz[threadIdx.x + 768] = z;
    }
    __syncthreads();

    int ebX = nbase * 16;
    int eb0 = ptr[nbase + 0], eb1 = ptr[nbase + 1], eb2 = ptr[nbase + 2],
        eb3 = ptr[nbase + 3], eb4 = ptr[nbase + 4];
    bool fixed16 = (eb0 == ebX) && (eb1 == ebX + 16) && (eb2 == ebX + 32) &&
                   (eb3 == ebX + 48) && (eb4 == ebX + 64);

    if (fixed16) {
        const int* sp = sidx + ebX;            // wave-uniform base -> s_load path
        u64 tp0 = typ4[nbase + 0], tp1 = typ4[nbase + 1],
            tp2 = typ4[nbase + 2], tp3 = typ4[nbase + 3];

        unsigned short xvA[16], xvB[16];
        int sA[16], sB[16];

// scalar source fetch for node nn (uniform -> SGPRs)
#define SLOAD(sarr, nn)                                                       \
        _Pragma("unroll")                                                     \
        for (int ee = 0; ee < 16; ++ee) sarr[ee] = sp[(nn) * 16 + ee];
// gather loads: uniform base + shared vaddr (saddr form)
#define LOADN(buf, sarr)                                                      \
        _Pragma("unroll")                                                     \
        for (int ee = 0; ee < 16; ++ee)                                       \
            buf[ee] = xb[(size_t)(unsigned)sarr[ee] * 64 + lane];
// run-boundary flush accumulate: branches wave-uniform (tp is scalar)
#define FLUSHACC(buf, nn, tp)                                                 \
        {                                                                     \
            int row_ = wave * 4 + (nn);                                       \
            unsigned int vlx_ = ((unsigned int)lane * 2u)                     \
                                ^ (((unsigned int)(row_ & 7)) << 4);          \
            unsigned int rb_ = (unsigned int)row_ * 1024u;                    \
            float s_ = 0.f;                                                   \
            _Pragma("unroll")                                                 \
            for (int ee = 0; ee < 16; ++ee) {                                 \
                s_ += bf2f(buf[ee]);                                          \
                int tcur_ = (int)((tp >> (4 * ee)) & 0xF);                    \
                int tnxt_ = (ee == 15) ? 16 : (int)((tp >> (4 * ee + 4)) & 0xF); \
                if (tcur_ != tnxt_) {                                         \
                    unsigned int byte_ = rb_ + (unsigned int)tcur_ * 128u + vlx_; \
                    *reinterpret_cast<unsigned short*>(sb + byte_) = f2bf(s_); \
                    s_ = 0.f;                                                 \
                }                                                             \
            }                                                                 \
        }

        SLOAD(sA, 0); LOADN(xvA, sA);
        SLOAD(sB, 1); LOADN(xvB, sB);
        SLOAD(sA, 2); FLUSHACC(xvA, 0, tp0); LOADN(xvA, sA);
        SLOAD(sB, 3); FLUSHACC(xvB, 1, tp1); LOADN(xvB, sB);
        FLUSHACC(xvA, 2, tp2);
        FLUSHACC(xvB, 3, tp3);
#undef SLOAD
#undef LOADN
#undef FLUSHACC
    } else {
        // -------- generic path: unsorted, 8-register dispatch --------
        int l16 = lane & 15;
        int ebs[5] = {eb0, eb1, eb2, eb3, eb4};
        for (int nn = 0; nn < 4; ++nn) {
            int eb = ebs[nn], en = ebs[nn + 1];
            float s0=0.f,s1=0.f,s2=0.f,s3=0.f,s4=0.f,s5=0.f,s6=0.f,s7=0.f;
            for (int e = eb; e < en; e += 16) {
                int m = en - e; if (m > 16) m = 16;
                int vi = 0, vt = 0;
                if (l16 < m) { vi = idx[e + l16]; vt = et[e + l16]; }
                for (int ee = 0; ee < m; ++ee) {
                    int src = __builtin_amdgcn_readlane(vi, ee);
                    int t   = __builtin_amdgcn_readlane(vt, ee);
                    float v = bf2f(xb[src * 64 + lane]);
                    if      (t == 0) s0 += v;
                    else if (t == 1) s1 += v;
                    else if (t == 2) s2 += v;
                    else if (t == 3) s3 += v;
                    else if (t == 4) s4 += v;
                    else if (t == 5) s5 += v;
                    else if (t == 6) s6 += v;
                    else             s7 += v;
                }
            }
            int row = wave * 4 + nn;
            unsigned int vlx = ((unsigned int)lane * 2u)
                               ^ (((unsigned int)(row & 7)) << 4);
            unsigned int rb = (unsigned int)row * 1024u;
            float sv[8] = {s0,s1,s2,s3,s4,s5,s6,s7};
#pragma unroll
            for (int r = 0; r < 8; ++r) {
                unsigned int byte = rb + (unsigned int)r * 128u + vlx;
                *reinterpret_cast<unsigned short*>(sb + byte) = f2bf(sv[r]);
            }
        }
    }
    __syncthreads();

    // ---------- MFMA phase: wave handles N-slice nt = wave ----------
    int nt = wave;
    f32x4 acc = {0.f,0.f,0.f,0.f};
    unsigned int arow  = (unsigned int)(lane & 15);
    unsigned int abase = arow * 1024u + (unsigned int)((lane >> 4) * 16);
    unsigned int axor  = (arow & 7u) << 4;
#pragma unroll 4
    for (int kt = 0; kt < 16; ++kt) {
        unsigned int abyte = (abase + (unsigned int)kt * 64u) ^ axor;
        bf16x8 a = *reinterpret_cast<const bf16x8*>(sb + abyte);
        bf16x8 b = wf[(kt * 4 + nt) * 64 + lane];
        acc = __builtin_amdgcn_mfma_f32_16x16x32_bf16(a, b, acc, 0, 0, 0);
    }

    // ---------- epilogue: /deg, history overwrite, write both outputs ----------
    int col   = nt * 16 + (lane & 15);
    int rquad = (lane >> 4) * 4;
#pragma unroll
    for (int j = 0; j < 4; ++j) {
        int node = n0 + rquad + j;
        float invd = 1.0f / (float)(ptr[node + 1] - ptr[node]);
        float v = acc[j] * invd;
        if (hmap[node] != -1) v = hbuf[node * 64 + col];
        out[node * 64 + col] = v;
        out[NNODE * 64 + node * 64 + col] = v;
    }
}

extern "C" void kernel_launch(void* const* d_in, const int* in_sizes, int n_in,
                              void* d_out, int out_size, void* d_ws, size_t ws_size,
                              hipStream_t stream) {
    (void)in_sizes; (void)n_in; (void)out_size; (void)ws_size;
    const float* x    = (const float*)d_in[0];
    const float* W    = (const float*)d_in[1];
    const int*   ptr  = (const int*)d_in[2];
    const int*   idx  = (const int*)d_in[3];
    const int*   et   = (const int*)d_in[4];
    const int*   hmap = (const int*)d_in[6];
    const float* hbuf = (const float*)d_in[7];
    float* out = (float*)d_out;

    // workspace: xb 12.8MB | wf 64KB | sidx 6.4MB | typ4 800KB  (all 64B-aligned)
    char* w = (char*)d_ws;
    unsigned short* xb  = (unsigned short*)w;
    unsigned short* wfu = (unsigned short*)(w + 12800000);
    int*            sidx= (int*)(w + 12865536);
    u64*            tp4 = (u64*)(w + 19265536);

    k_prep<<<dim3(6657), dim3(256), 0, stream>>>(x, W, ptr, idx, et, xb, wfu, sidx, tp4);
    k_main<<<dim3(NGRP), dim3(256), 0, stream>>>(
        xb, (const bf16x8*)wfu, ptr, sidx, tp4, idx, et, hmap, hbuf, out);
}

// Round 9
// 71.721 us; speedup vs baseline: 1.1531x; 1.1531x over previous
//
#include <hip/hip_runtime.h>
#include <hip/hip_bf16.h>

#define NNODE 100000
#define CIN   64
#define CHID  64
#define NREL  8
#define NGRP  6250     // NNODE / 16

typedef __attribute__((ext_vector_type(8))) short bf16x8;
typedef __attribute__((ext_vector_type(4))) float f32x4;
typedef unsigned long long u64;

__device__ __forceinline__ unsigned short f2bf(float f) {
    __hip_bfloat16 h = __float2bfloat16(f);
    return __builtin_bit_cast(unsigned short, h);
}
__device__ __forceinline__ float bf2f(unsigned short u) {
    unsigned int v = ((unsigned int)u) << 16;
    return __builtin_bit_cast(float, v);
}

// ---- prep: x (f32) -> xb (bf16) ----
__global__ void k_prep_x(const float* __restrict__ x, unsigned short* __restrict__ xb) {
    int i = (blockIdx.x * 256 + threadIdx.x) * 4;
    if (i >= NNODE * CIN) return;
    float4 v = *reinterpret_cast<const float4*>(x + i);
    ushort4 o;
    o.x = f2bf(v.x); o.y = f2bf(v.y); o.z = f2bf(v.z); o.w = f2bf(v.w);
    *reinterpret_cast<ushort4*>(xb + i) = o;
}

// ---- prep: per-node counting sort of edges by type (deg==16 fast case) ----
__global__ void k_sort(const int* __restrict__ ptr, const int* __restrict__ idx,
                       const int* __restrict__ et, int* __restrict__ sidx,
                       u64* __restrict__ typ4) {
    int node = blockIdx.x * 256 + threadIdx.x;
    if (node >= NNODE) return;
    int eb = ptr[node], en = ptr[node + 1];
    if (en - eb != 16) { typ4[node] = 0; return; }
    u64 cnt = 0;
#pragma unroll
    for (int ee = 0; ee < 16; ++ee)
        cnt += 1ull << (8 * et[eb + ee]);
    u64 pre = cnt * 0x0101010101010100ull;   // exclusive byte prefix sums
    u64 occ = 0, tp = 0;
#pragma unroll
    for (int ee = 0; ee < 16; ++ee) {
        int te = et[eb + ee];
        int sh = te * 8;
        int pos = (int)((pre >> sh) & 0xFF) + (int)((occ >> sh) & 0xFF);
        occ += 1ull << sh;
        sidx[eb + pos] = idx[eb + ee];
        tp |= (u64)te << (4 * pos);
    }
    typ4[node] = tp;
}

// ---- prep: W (f32 [8][64][64]) -> B-fragment-ordered bf16, flat k = r*64 + ki ----
__global__ void k_prep_w(const float* __restrict__ W, unsigned short* __restrict__ wf) {
    int tid = blockIdx.x * 256 + threadIdx.x;
    if (tid >= 64 * 64) return;
    int tile = tid >> 6, lane = tid & 63;
    int kt = tile >> 2, nt = tile & 3;
    int kbase = kt * 32 + (lane >> 4) * 8;
    int col = nt * 16 + (lane & 15);
    unsigned short v[8];
#pragma unroll
    for (int j = 0; j < 8; ++j)
        v[j] = f2bf(W[(kbase + j) * 64 + col]);
    ushort4* dst = reinterpret_cast<ushort4*>(wf + (size_t)tid * 8);
    ushort4 lo, hi;
    lo.x = v[0]; lo.y = v[1]; lo.z = v[2]; lo.w = v[3];
    hi.x = v[4]; hi.y = v[5]; hi.z = v[6]; hi.w = v[7];
    dst[0] = lo; dst[1] = hi;
}

// ---- main: block = 4 waves share one 16-node group; S[16][512] bf16 swizzled ----
// Fast path: scalar-sourced gather in 16-load batches; a liveness-binder asm after
// each batch forces all 16 loads issued + held in distinct VGPRs, with the compiler's
// precise waitcnt leaving the NEXT batch in flight (vmcnt(16)) -> true MLP ~32/wave.
__launch_bounds__(256, 8)
__global__ void k_main(const unsigned short* __restrict__ xb,
                       const bf16x8* __restrict__ wf,
                       const int* __restrict__ ptr,
                       const int* __restrict__ sidx,
                       const u64* __restrict__ typ4,
                       const int* __restrict__ idx,
                       const int* __restrict__ et,
                       const int* __restrict__ hmap,
                       const float* __restrict__ hbuf,
                       float* __restrict__ out) {
    __shared__ __align__(16) unsigned short S[8192];   // 16 rows x 512 k, 16 KB

    int wave = __builtin_amdgcn_readfirstlane((int)(threadIdx.x >> 6));
    int lane = threadIdx.x & 63;
    int n0 = blockIdx.x * 16;
    int nbase = n0 + wave * 4;
    char* sb = reinterpret_cast<char*>(&S[0]);

    // zero S (types with no edges must read as 0)
    {
        f32x4 z = {0.f, 0.f, 0.f, 0.f};
        f32x4* sz = reinterpret_cast<f32x4*>(sb);
        sz[threadIdx.x]       = z;
        sz[threadIdx.x + 256] = z;
        sz[threadIdx.x + 512] = z;
        sz[threadIdx.x + 768] = z;
    }
    __syncthreads();

    int ebX = nbase * 16;
    int eb0 = ptr[nbase + 0], eb1 = ptr[nbase + 1], eb2 = ptr[nbase + 2],
        eb3 = ptr[nbase + 3], eb4 = ptr[nbase + 4];
    bool fixed16 = (eb0 == ebX) && (eb1 == ebX + 16) && (eb2 == ebX + 32) &&
                   (eb3 == ebX + 48) && (eb4 == ebX + 64);

    if (fixed16) {
        const int* sp = sidx + ebX;            // wave-uniform base -> s_load path
        u64 tp0 = typ4[nbase + 0], tp1 = typ4[nbase + 1],
            tp2 = typ4[nbase + 2], tp3 = typ4[nbase + 3];

        unsigned short bA[16], bB[16], bC[16], bD[16];

// issue one 16-load batch (scalar base per edge, shared vaddr = lane*2)
#define LD16(b, nn)                                                           \
        _Pragma("unroll")                                                     \
        for (int ee = 0; ee < 16; ++ee) {                                     \
            const unsigned short* p_ = xb + (size_t)(unsigned)sp[(nn)*16+ee] * 64; \
            b[ee] = p_[lane];                                                 \
        }
// liveness binder: all 16 values must be loaded-and-live here; memory clobber
// stops later loads from sinking above/below incorrectly. Compiler emits a
// counted vmcnt leaving subsequently-issued loads in flight.
#define BIND16(b)                                                             \
        asm volatile("" :: "v"(b[0]), "v"(b[1]), "v"(b[2]), "v"(b[3]),        \
                           "v"(b[4]), "v"(b[5]), "v"(b[6]), "v"(b[7]),        \
                           "v"(b[8]), "v"(b[9]), "v"(b[10]), "v"(b[11]),      \
                           "v"(b[12]), "v"(b[13]), "v"(b[14]), "v"(b[15])     \
                     : "memory");
// run-boundary flush accumulate (branches wave-uniform, tp is scalar)
#define FLUSHACC(b, nn, tp)                                                   \
        {                                                                     \
            int row_ = wave * 4 + (nn);                                       \
            unsigned int vlx_ = ((unsigned int)lane * 2u)                     \
                                ^ (((unsigned int)(row_ & 7)) << 4);          \
            unsigned int rb_ = (unsigned int)row_ * 1024u;                    \
            float s_ = 0.f;                                                   \
            _Pragma("unroll")                                                 \
            for (int ee = 0; ee < 16; ++ee) {                                 \
                s_ += bf2f(b[ee]);                                            \
                int tcur_ = (int)((tp >> (4 * ee)) & 0xF);                    \
                int tnxt_ = (ee == 15) ? 16 : (int)((tp >> (4 * ee + 4)) & 0xF); \
                if (tcur_ != tnxt_) {                                         \
                    unsigned int byte_ = rb_ + (unsigned int)tcur_ * 128u + vlx_; \
                    *reinterpret_cast<unsigned short*>(sb + byte_) = f2bf(s_); \
                    s_ = 0.f;                                                 \
                }                                                             \
            }                                                                 \
        }

        LD16(bA, 0);
        LD16(bB, 1);
        BIND16(bA);                 // waits bA only -> bB stays in flight
        FLUSHACC(bA, 0, tp0);
        LD16(bC, 2);
        BIND16(bB);                 // bC stays in flight
        FLUSHACC(bB, 1, tp1);
        LD16(bD, 3);
        BIND16(bC);                 // bD stays in flight
        FLUSHACC(bC, 2, tp2);
        BIND16(bD);
        FLUSHACC(bD, 3, tp3);
#undef LD16
#undef BIND16
#undef FLUSHACC
    } else {
        // -------- generic path: unsorted, 8-register dispatch --------
        int l16 = lane & 15;
        int ebs[5] = {eb0, eb1, eb2, eb3, eb4};
        for (int nn = 0; nn < 4; ++nn) {
            int eb = ebs[nn], en = ebs[nn + 1];
            float s0=0.f,s1=0.f,s2=0.f,s3=0.f,s4=0.f,s5=0.f,s6=0.f,s7=0.f;
            for (int e = eb; e < en; e += 16) {
                int m = en - e; if (m > 16) m = 16;
                int vi = 0, vt = 0;
                if (l16 < m) { vi = idx[e + l16]; vt = et[e + l16]; }
                for (int ee = 0; ee < m; ++ee) {
                    int src = __builtin_amdgcn_readlane(vi, ee);
                    int t   = __builtin_amdgcn_readlane(vt, ee);
                    float v = bf2f(xb[src * 64 + lane]);
                    if      (t == 0) s0 += v;
                    else if (t == 1) s1 += v;
                    else if (t == 2) s2 += v;
                    else if (t == 3) s3 += v;
                    else if (t == 4) s4 += v;
                    else if (t == 5) s5 += v;
                    else if (t == 6) s6 += v;
                    else             s7 += v;
                }
            }
            int row = wave * 4 + nn;
            unsigned int vlx = ((unsigned int)lane * 2u)
                               ^ (((unsigned int)(row & 7)) << 4);
            unsigned int rb = (unsigned int)row * 1024u;
            float sv[8] = {s0,s1,s2,s3,s4,s5,s6,s7};
#pragma unroll
            for (int r = 0; r < 8; ++r) {
                unsigned int byte = rb + (unsigned int)r * 128u + vlx;
                *reinterpret_cast<unsigned short*>(sb + byte) = f2bf(sv[r]);
            }
        }
    }
    __syncthreads();

    // ---------- MFMA phase: wave handles N-slice nt = wave ----------
    int nt = wave;
    f32x4 acc = {0.f,0.f,0.f,0.f};
    unsigned int arow  = (unsigned int)(lane & 15);
    unsigned int abase = arow * 1024u + (unsigned int)((lane >> 4) * 16);
    unsigned int axor  = (arow & 7u) << 4;
#pragma unroll 4
    for (int kt = 0; kt < 16; ++kt) {
        unsigned int abyte = (abase + (unsigned int)kt * 64u) ^ axor;
        bf16x8 a = *reinterpret_cast<const bf16x8*>(sb + abyte);
        bf16x8 b = wf[(kt * 4 + nt) * 64 + lane];
        acc = __builtin_amdgcn_mfma_f32_16x16x32_bf16(a, b, acc, 0, 0, 0);
    }

    // ---------- epilogue: /deg, history overwrite, write both outputs ----------
    int col   = nt * 16 + (lane & 15);
    int rquad = (lane >> 4) * 4;
#pragma unroll
    for (int j = 0; j < 4; ++j) {
        int node = n0 + rquad + j;
        float invd = 1.0f / (float)(ptr[node + 1] - ptr[node]);
        float v = acc[j] * invd;
        if (hmap[node] != -1) v = hbuf[node * 64 + col];
        out[node * 64 + col] = v;
        out[NNODE * 64 + node * 64 + col] = v;
    }
}

extern "C" void kernel_launch(void* const* d_in, const int* in_sizes, int n_in,
                              void* d_out, int out_size, void* d_ws, size_t ws_size,
                              hipStream_t stream) {
    (void)in_sizes; (void)n_in; (void)out_size; (void)ws_size;
    const float* x    = (const float*)d_in[0];
    const float* W    = (const float*)d_in[1];
    const int*   ptr  = (const int*)d_in[2];
    const int*   idx  = (const int*)d_in[3];
    const int*   et   = (const int*)d_in[4];
    const int*   hmap = (const int*)d_in[6];
    const float* hbuf = (const float*)d_in[7];
    float* out = (float*)d_out;

    // workspace: xb 12.8MB | wf 64KB | sidx 6.4MB | typ4 800KB  (all 64B-aligned)
    char* w = (char*)d_ws;
    unsigned short* xb  = (unsigned short*)w;
    unsigned short* wfu = (unsigned short*)(w + 12800000);
    int*            sidx= (int*)(w + 12865536);
    u64*            tp4 = (u64*)(w + 19265536);

    k_prep_x<<<dim3((NNODE * CIN / 4 + 255) / 256), dim3(256), 0, stream>>>(x, xb);
    k_sort<<<dim3((NNODE + 255) / 256), dim3(256), 0, stream>>>(ptr, idx, et, sidx, tp4);
    k_prep_w<<<dim3(16), dim3(256), 0, stream>>>(W, wfu);
    k_main<<<dim3(NGRP), dim3(256), 0, stream>>>(
        xb, (const bf16x8*)wfu, ptr, sidx, tp4, idx, et, hmap, hbuf, out);
}